// Round 4
// baseline (77.359 us; speedup 1.0000x reference)
//
#include <hip/hip_runtime.h>
#include <stdint.h>

#define BB 256
#define CC 64
#define CVV 4
#define LL 2048
#define NCHUNK 2              // blocks per batch
#define NR ((CC + CVV) / NCHUNK)  // 34 rows per block

#define WAITV(n) asm volatile("s_waitcnt vmcnt(" #n ")" ::: "memory")

__device__ __forceinline__ void ce_desc(unsigned long long* key, int i, int j,
                                        bool descBlk) {
  unsigned long long a = key[i], c = key[j];
  bool sw = descBlk ? (a < c) : (a > c);
  if (sw) { key[i] = c; key[j] = a; }
}

// Async global->LDS, 16 B per lane. LDS dest = wave-uniform base + lane*16
// (HW-added); global src is per-lane.
__device__ __forceinline__ void issue_row(const float* src_lane,
                                          float* lds_wave_base) {
  __builtin_amdgcn_global_load_lds(
      (const __attribute__((address_space(1))) void*)src_lane,
      (__attribute__((address_space(3))) void*)lds_wave_base, 16, 0, 0);
}

// ---------------------------------------------------------------------------
// Fused kernel: block = (batch b, chunk c of 34 rows), 512 threads.
// Phase 1: stable descending argsort of rand_f (bitonic on 64-bit composite
//          keys ord(rand_f)<<32 | (L-1-idx), wave-segment optimized), perm
//          entries for this thread's 4 output positions -> int4 register,
//          mask_t written directly (chunk-0 block only).
// Phase 2: gather 34 rows through a 4-buffer LDS ring fed by
//          global_load_lds, software-pipelined 3 rows deep with counted
//          s_waitcnt vmcnt(N) (loads+stores retire in order: steady N=5)
//          and ONE raw s_barrier per row. Reissue into buf[(rr+3)&3] is safe:
//          that buffer was last read in iter rr-1, and all waves crossed the
//          iter-rr barrier after reading it.
// ---------------------------------------------------------------------------
__global__ __launch_bounds__(512, 4) void trimmer_kernel(
    const float* __restrict__ x, const float* __restrict__ v,
    const void* __restrict__ mask, const float* __restrict__ rnd,
    float* __restrict__ xo, float* __restrict__ vo, float* __restrict__ mo) {
  __shared__ union {
    unsigned long long key[LL];   // 16 KB (sort phase)
    float rows[4][LL];            // 32 KB (gather ring)
  } sh;
  __shared__ int cnt;
  __shared__ unsigned detf;

  const int b = blockIdx.x >> 1;
  const int c = blockIdx.x & 1;
  const int tid = threadIdx.x;
  if (tid == 0) { cnt = 0; detf = 0; }
  __syncthreads();

  // --- self-detect bool-mask marshaling from words [b*512, b*512+512) ---
  {
    unsigned val = ((const unsigned*)mask)[b * 512 + tid];
    unsigned f = (val == 0x3F800000u) ? 2u : (val > 1u ? 1u : 0u);
    if (f) atomicOr(&detf, f);
  }
  __syncthreads();
  const unsigned fl = detf;
  const int layout = (fl & 1u) ? 1 : ((fl & 2u) ? 2 : 0);

  // --- build composite keys ---
  int local = 0;
  for (int l = tid; l < LL; l += 512) {
    bool m;
    if (layout == 1)      m = ((const unsigned char*)mask)[b * LL + l] != 0;
    else if (layout == 2) m = ((const float*)mask)[b * LL + l] != 0.0f;
    else                  m = ((const int*)mask)[b * LL + l] != 0;
    float rf = m ? -1.0f : rnd[b * LL + l];
    unsigned u = __float_as_uint(rf);
    u = (u & 0x80000000u) ? ~u : (u | 0x80000000u);  // order-preserving map
    sh.key[l] = ((unsigned long long)u << 32) | (unsigned)(LL - 1 - l);
    local += m ? 1 : 0;
  }
  if (local) atomicAdd(&cnt, local);
  __syncthreads();

  // --- bitonic sort, descending; wave w owns sh.key[w*256 .. w*256+255] ---
  const int w = tid >> 6;
  const int lane = tid & 63;

  for (int size = 2; size <= 256; size <<= 1) {
    for (int stride = size >> 1; stride > 0; stride >>= 1) {
#pragma unroll
      for (int pp = 0; pp < 2; ++pp) {
        int p = w * 128 + pp * 64 + lane;
        int i = ((p & ~(stride - 1)) << 1) | (p & (stride - 1));
        ce_desc(sh.key, i, i + stride, (i & size) == 0);
      }
      __builtin_amdgcn_wave_barrier();
    }
  }
  __syncthreads();

  for (int size = 512; size <= 2048; size <<= 1) {
    for (int stride = size >> 1; stride >= 256; stride >>= 1) {
      for (int t = tid; t < LL / 2; t += 512) {
        int i = ((t & ~(stride - 1)) << 1) | (t & (stride - 1));
        ce_desc(sh.key, i, i + stride, (i & size) == 0);
      }
      __syncthreads();
    }
    for (int stride = 128; stride > 0; stride >>= 1) {
#pragma unroll
      for (int pp = 0; pp < 2; ++pp) {
        int p = w * 128 + pp * 64 + lane;
        int i = ((p & ~(stride - 1)) << 1) | (p & (stride - 1));
        ce_desc(sh.key, i, i + stride, (i & size) == 0);
      }
      __builtin_amdgcn_wave_barrier();
    }
    __syncthreads();
  }

  // --- extract perm for output positions 4*tid..4*tid+3; write mask_t ---
  const int maxlen = cnt > 1 ? cnt : 1;              // jnp.maximum(count, 1)
  const unsigned ordNeg1 = ~__float_as_uint(-1.0f);  // ord(-1.0)
  int sv[4];
  float mf[4];
#pragma unroll
  for (int k = 0; k < 4; ++k) {
    int j = tid * 4 + k;
    unsigned long long k2 = sh.key[j];
    int idx = (LL - 1) - (int)(unsigned)(k2 & 0xFFFFFFFFull);
    bool masked = ((unsigned)(k2 >> 32)) == ordNeg1;
    bool keep = j < maxlen;
    sv[k] = idx | (masked ? (1 << 11) : 0) | (keep ? (1 << 12) : 0);
    mf[k] = (keep && masked) ? 1.0f : 0.0f;
  }
  const int4 s = make_int4(sv[0], sv[1], sv[2], sv[3]);
  if (c == 0)
    ((float4*)(mo + (size_t)b * LL))[tid] = make_float4(mf[0], mf[1], mf[2], mf[3]);
  __syncthreads();  // all key reads done before ring buffers overwrite union

  // --- gather pipeline ---
  float* const ring = &sh.rows[0][0];
  float* const lds_wave = ring + w * 256;  // wave-uniform base within a buffer
  const float* const xs = x + (size_t)b * CC * LL;
  const float* const vs = v + (size_t)b * CVV * LL;
  float* const xd = xo + (size_t)b * CC * LL;
  float* const vd = vo + (size_t)b * CVV * LL;
  const int lane4 = tid * 4;

#pragma unroll 1
  for (int k = 0; k < 3; ++k) {  // prologue: rows 0..2 in flight
    int rg = c * NR + k;
    const float* src = (rg < CC) ? xs + (size_t)rg * LL
                                 : vs + (size_t)(rg - CC) * LL;
    issue_row(src + lane4, lds_wave + k * LL);
  }

#pragma unroll 1
  for (int rr = 0; rr < NR; ++rr) {
    // Counted wait: per-wave in-order VMEM queue holds (ahead of this row's
    // load) S(rr-3), L(rr+1), S(rr-2), L(rr+2), S(rr-1) -> steady 5.
    if (rr == 0)            WAITV(2);
    else if (rr == 1)       WAITV(3);
    else if (rr == 2)       WAITV(4);
    else if (rr >= NR - 2)  WAITV(0);   // conservative tail drain
    else                    WAITV(5);
    __builtin_amdgcn_s_barrier();       // all waves' row-rr chunks in LDS

    if (rr + 3 < NR) {                  // reissue into buf last read at rr-1
      int rg = c * NR + rr + 3;
      const float* src = (rg < CC) ? xs + (size_t)rg * LL
                                   : vs + (size_t)(rg - CC) * LL;
      issue_row(src + lane4, lds_wave + ((rr + 3) & 3) * LL);
    }

    const float* buf = ring + (rr & 3) * LL;
    float4 o;
    o.x = (s.x & (1 << 12)) ? buf[s.x & 0x7FF] : 0.0f;
    o.y = (s.y & (1 << 12)) ? buf[s.y & 0x7FF] : 0.0f;
    o.z = (s.z & (1 << 12)) ? buf[s.z & 0x7FF] : 0.0f;
    o.w = (s.w & (1 << 12)) ? buf[s.w & 0x7FF] : 0.0f;

    int rg = c * NR + rr;
    float* dst = (rg < CC) ? xd + (size_t)rg * LL
                           : vd + (size_t)(rg - CC) * LL;
    ((float4*)dst)[tid] = o;
  }
}

extern "C" void kernel_launch(void* const* d_in, const int* in_sizes, int n_in,
                              void* d_out, int out_size, void* d_ws, size_t ws_size,
                              hipStream_t stream) {
  const float* x    = (const float*)d_in[0];
  const float* v    = (const float*)d_in[1];
  const void*  mask = d_in[2];
  const float* rnd  = (const float*)d_in[3];

  float* xo = (float*)d_out;                  // B*C*L
  float* vo = xo + (size_t)BB * CC * LL;      // B*CV*L
  float* mo = vo + (size_t)BB * CVV * LL;     // B*1*L

  trimmer_kernel<<<BB * NCHUNK, 512, 0, stream>>>(x, v, mask, rnd, xo, vo, mo);
}

// Round 5
// 72.262 us; speedup vs baseline: 1.0705x; 1.0705x over previous
//
#include <hip/hip_runtime.h>
#include <stdint.h>

#define BB 256
#define CC 64
#define CVV 4
#define LL 2048
#define GROUPS 4                   // gather blocks per batch
#define NRG ((CC + CVV) / GROUPS)  // 17 rows per gather block

#define WAITV(n) asm volatile("s_waitcnt vmcnt(" #n ")" ::: "memory")

__device__ __forceinline__ void ce_desc(unsigned long long* key, int i, int j,
                                        bool descBlk) {
  unsigned long long a = key[i], c = key[j];
  bool sw = descBlk ? (a < c) : (a > c);
  if (sw) { key[i] = c; key[j] = a; }
}

// ---------------------------------------------------------------------------
// Kernel 1: per-batch stable descending argsort of rand_f via bitonic sort of
// 64-bit composite keys (ord(rand_f)<<32 | (L-1-idx)) in LDS, wave-segment
// optimized (stride<=128 substages are wave-local; ~10 block barriers total).
// Mask layout self-detected per block from a disjoint 512-word slice.
// Writes stage ints (idx | masked<<11 | keep<<12) vectorized int4, and the
// final mask_t floats (float4) when mout != nullptr.
// ---------------------------------------------------------------------------
__global__ __launch_bounds__(512) void sortperm_kernel(const void* mask,
                                                       const float* rnd,
                                                       int* stage,
                                                       float* mout) {
  __shared__ unsigned long long key[LL];
  __shared__ int cnt;
  __shared__ unsigned detf;
  const int b = blockIdx.x;
  const int tid = threadIdx.x;
  if (tid == 0) { cnt = 0; detf = 0; }
  __syncthreads();

  {
    unsigned val = ((const unsigned*)mask)[b * 512 + tid];
    unsigned f = (val == 0x3F800000u) ? 2u : (val > 1u ? 1u : 0u);
    if (f) atomicOr(&detf, f);
  }
  __syncthreads();
  const unsigned fl = detf;
  const int layout = (fl & 1u) ? 1 : ((fl & 2u) ? 2 : 0);

  int local = 0;
  for (int l = tid; l < LL; l += 512) {
    bool m;
    if (layout == 1)      m = ((const unsigned char*)mask)[b * LL + l] != 0;
    else if (layout == 2) m = ((const float*)mask)[b * LL + l] != 0.0f;
    else                  m = ((const int*)mask)[b * LL + l] != 0;
    float rf = m ? -1.0f : rnd[b * LL + l];
    unsigned u = __float_as_uint(rf);
    u = (u & 0x80000000u) ? ~u : (u | 0x80000000u);  // order-preserving map
    key[l] = ((unsigned long long)u << 32) | (unsigned)(LL - 1 - l);
    local += m ? 1 : 0;
  }
  if (local) atomicAdd(&cnt, local);
  __syncthreads();

  const int w = tid >> 6;    // wave id 0..7 owns key[w*256 .. w*256+255]
  const int lane = tid & 63;

  for (int size = 2; size <= 256; size <<= 1) {
    for (int stride = size >> 1; stride > 0; stride >>= 1) {
#pragma unroll
      for (int pp = 0; pp < 2; ++pp) {
        int p = w * 128 + pp * 64 + lane;
        int i = ((p & ~(stride - 1)) << 1) | (p & (stride - 1));
        ce_desc(key, i, i + stride, (i & size) == 0);
      }
      __builtin_amdgcn_wave_barrier();
    }
  }
  __syncthreads();

  for (int size = 512; size <= 2048; size <<= 1) {
    for (int stride = size >> 1; stride >= 256; stride >>= 1) {
      for (int t = tid; t < LL / 2; t += 512) {
        int i = ((t & ~(stride - 1)) << 1) | (t & (stride - 1));
        ce_desc(key, i, i + stride, (i & size) == 0);
      }
      __syncthreads();
    }
    for (int stride = 128; stride > 0; stride >>= 1) {
#pragma unroll
      for (int pp = 0; pp < 2; ++pp) {
        int p = w * 128 + pp * 64 + lane;
        int i = ((p & ~(stride - 1)) << 1) | (p & (stride - 1));
        ce_desc(key, i, i + stride, (i & size) == 0);
      }
      __builtin_amdgcn_wave_barrier();
    }
    __syncthreads();
  }

  // --- extract positions 4*tid..4*tid+3; vectorized writes ---
  const int maxlen = cnt > 1 ? cnt : 1;              // jnp.maximum(count, 1)
  const unsigned ordNeg1 = ~__float_as_uint(-1.0f);  // ord(-1.0)
  int sv[4];
  float mf[4];
#pragma unroll
  for (int k = 0; k < 4; ++k) {
    int j = tid * 4 + k;
    unsigned long long k2 = key[j];
    int idx = (LL - 1) - (int)(unsigned)(k2 & 0xFFFFFFFFull);
    bool masked = ((unsigned)(k2 >> 32)) == ordNeg1;
    bool keep = j < maxlen;
    sv[k] = idx | (masked ? (1 << 11) : 0) | (keep ? (1 << 12) : 0);
    mf[k] = (keep && masked) ? 1.0f : 0.0f;
  }
  ((int4*)(stage + (size_t)b * LL))[tid] = make_int4(sv[0], sv[1], sv[2], sv[3]);
  if (mout)
    ((float4*)(mout + (size_t)b * LL))[tid] =
        make_float4(mf[0], mf[1], mf[2], mf[3]);
}

// ---------------------------------------------------------------------------
// Kernel 2: gather x/v rows through the staged permutation.
// Block = (batch b, group g of 17 rows), 256 threads (4 waves), 4-buffer LDS
// ring fed by global_load_lds (2 issues/row), software-pipelined 3 rows deep
// with counted s_waitcnt vmcnt(N): per-wave in-order VMEM queue per iter is
// {2 loads, 2 stores}; needing L2(rr) retired leaves 10 newer ops in steady
// state (prologue 4/6/8, tail 8/6 — the queue is never drained). One raw
// s_barrier per row. Reissue into slot (rr+3)&3 is safe: it was last read in
// iter rr-1 and all waves crossed the iter-rr barrier since.
// XCD-chunked block decode: XCD x = blockIdx%8 owns batches [x*32, x*32+32),
// so the 4 g-blocks of a batch share one XCD's L2 for the stage row.
// ---------------------------------------------------------------------------
__global__ __launch_bounds__(256, 4) void gather_kernel(
    const float* __restrict__ x, const float* __restrict__ v,
    const int* __restrict__ stage, float* __restrict__ xo,
    float* __restrict__ vo) {
  __shared__ float ring[4][LL];  // 32 KB
  const int Lid = blockIdx.x;
  const int xcd = Lid & 7;
  const int c = Lid >> 3;            // 0..127
  const int b = xcd * 32 + (c >> 2); // batch
  const int g = c & 3;               // row group
  const int tid = threadIdx.x;
  const int w = tid >> 6;            // wave id (uniform)

  const int4* st4 = (const int4*)(stage + (size_t)b * LL);
  const int4 s0 = st4[tid];
  const int4 s1 = st4[tid + 256];

  const float* const xs = x + (size_t)b * CC * LL;
  const float* const vs = v + (size_t)b * CVV * LL;
  float* const xd = xo + (size_t)b * CC * LL;
  float* const vd = vo + (size_t)b * CVV * LL;

#define SRCROW(rr) ((g * NRG + (rr)) < CC \
    ? xs + (size_t)(g * NRG + (rr)) * LL \
    : vs + (size_t)(g * NRG + (rr) - CC) * LL)
#define DSTROW(rr) ((g * NRG + (rr)) < CC \
    ? xd + (size_t)(g * NRG + (rr)) * LL \
    : vd + (size_t)(g * NRG + (rr) - CC) * LL)

#define ISSUE(rr) do { \
    const float* _src = SRCROW(rr); \
    float* _base = &ring[(rr) & 3][0] + w * 256; /* wave-uniform */ \
    __builtin_amdgcn_global_load_lds( \
        (const __attribute__((address_space(1))) void*)(_src + tid * 4), \
        (__attribute__((address_space(3))) void*)_base, 16, 0, 0); \
    __builtin_amdgcn_global_load_lds( \
        (const __attribute__((address_space(1))) void*)(_src + 1024 + tid * 4), \
        (__attribute__((address_space(3))) void*)(_base + 1024), 16, 0, 0); \
  } while (0)

  ISSUE(0); ISSUE(1); ISSUE(2);  // prologue: 3 rows (6 loads) in flight

#pragma unroll 1
  for (int rr = 0; rr < NRG; ++rr) {
    if (rr == 0)             WAITV(4);
    else if (rr == 1)        WAITV(6);
    else if (rr == 2)        WAITV(8);
    else if (rr == NRG - 2)  WAITV(8);
    else if (rr == NRG - 1)  WAITV(6);
    else                     WAITV(10);
    __builtin_amdgcn_s_barrier();  // all waves' row-rr chunks now in LDS

    if (rr + 3 < NRG) ISSUE(rr + 3);

    const float* buf = &ring[rr & 3][0];
    float4 o;
    o.x = (s0.x & (1 << 12)) ? buf[s0.x & 0x7FF] : 0.0f;
    o.y = (s0.y & (1 << 12)) ? buf[s0.y & 0x7FF] : 0.0f;
    o.z = (s0.z & (1 << 12)) ? buf[s0.z & 0x7FF] : 0.0f;
    o.w = (s0.w & (1 << 12)) ? buf[s0.w & 0x7FF] : 0.0f;
    float* dst = DSTROW(rr);
    ((float4*)dst)[tid] = o;
    o.x = (s1.x & (1 << 12)) ? buf[s1.x & 0x7FF] : 0.0f;
    o.y = (s1.y & (1 << 12)) ? buf[s1.y & 0x7FF] : 0.0f;
    o.z = (s1.z & (1 << 12)) ? buf[s1.z & 0x7FF] : 0.0f;
    o.w = (s1.w & (1 << 12)) ? buf[s1.w & 0x7FF] : 0.0f;
    ((float4*)dst)[tid + 256] = o;
  }
#undef ISSUE
#undef SRCROW
#undef DSTROW
}

// ---------------------------------------------------------------------------
// Kernel 3 (fallback only, when ws is too small and stage aliases the mask
// output): convert staged ints in place to the final mask floats.
// ---------------------------------------------------------------------------
__global__ __launch_bounds__(256) void maskout_kernel(int* stage,
                                                      float* mout) {
  const int i = blockIdx.x * 256 + threadIdx.x;
  int s = stage[i];
  mout[i] = ((s & (1 << 12)) && (s & (1 << 11))) ? 1.0f : 0.0f;
}

extern "C" void kernel_launch(void* const* d_in, const int* in_sizes, int n_in,
                              void* d_out, int out_size, void* d_ws, size_t ws_size,
                              hipStream_t stream) {
  const float* x    = (const float*)d_in[0];
  const float* v    = (const float*)d_in[1];
  const void*  mask = d_in[2];
  const float* rnd  = (const float*)d_in[3];

  float* xo = (float*)d_out;                  // B*C*L
  float* vo = xo + (size_t)BB * CC * LL;      // B*CV*L
  float* mo = vo + (size_t)BB * CVV * LL;     // B*1*L

  const bool use_ws = ws_size >= (size_t)BB * LL * sizeof(int);
  int* stage = use_ws ? (int*)d_ws : (int*)mo;

  sortperm_kernel<<<BB, 512, 0, stream>>>(mask, rnd, stage,
                                          use_ws ? mo : nullptr);
  gather_kernel<<<BB * GROUPS, 256, 0, stream>>>(x, v, stage, xo, vo);
  if (!use_ws)
    maskout_kernel<<<(BB * LL) / 256, 256, 0, stream>>>(stage, mo);
}